// Round 10
// baseline (408.068 us; speedup 1.0000x reference)
//
#include <hip/hip_runtime.h>
#include <hip/hip_bf16.h>

// ---------------- constants (problem shape) ----------------
#define B_   2
#define S_   2048
#define D_   1024
#define H_   16
#define DK_  64
#define DFF_ 4096
#define M_   (B_*S_)   // 4096 rows

typedef unsigned short u16;
typedef __attribute__((ext_vector_type(8))) short short8;
typedef __attribute__((ext_vector_type(4))) short bf16x4;
typedef __attribute__((ext_vector_type(4))) float floatx4;

__device__ __forceinline__ u16 f2bf(float f) {
    union { float f; unsigned u; } v; v.f = f;
    unsigned r = v.u + 0x7fffu + ((v.u >> 16) & 1u);
    return (u16)(r >> 16);
}
__device__ __forceinline__ u16 f2bf_fast(float f) {
    __hip_bfloat16 h = __float2bfloat16(f);
    return *reinterpret_cast<u16*>(&h);
}
__device__ __forceinline__ float b2f(u16 u) {
    union { unsigned u; float f; } v; v.u = ((unsigned)u) << 16; return v.f;
}
__device__ __forceinline__ float exp2_fast(float f) {
    return __builtin_amdgcn_exp2f(f);
}
__device__ __forceinline__ void g2l16(const u16* g, u16* l) {
    __builtin_amdgcn_global_load_lds((const __attribute__((address_space(1))) void*)g,
                                     (__attribute__((address_space(3))) void*)l,
                                     16, 0, 0);
}
__device__ __forceinline__ unsigned lds_off(const void* p) {
    return (unsigned)(unsigned long long)p;
}

#define TRB16(dst, va, IMM)                                                    \
    asm volatile("ds_read_b64_tr_b16 %0, %1 offset:" #IMM                      \
                 : "=v"(dst) : "v"(va))

// ------- fused fp32->bf16 conversion of x + weights, bias concat, mbias -----
__global__ __launch_bounds__(256) void cvt_all(
    const float* __restrict__ x,  const float* __restrict__ wq,
    const float* __restrict__ wk, const float* __restrict__ wv,
    const float* __restrict__ wo, const float* __restrict__ w1,
    const float* __restrict__ w2,
    const float* __restrict__ bq, const float* __restrict__ bk,
    const float* __restrict__ bv, const int* __restrict__ mask,
    u16* __restrict__ xb, u16* __restrict__ wqkvb, u16* __restrict__ wob,
    u16* __restrict__ w1b, u16* __restrict__ w2b,
    float* __restrict__ bqkv, float* __restrict__ mbias) {
    for (int i = blockIdx.x * 256 + threadIdx.x; i < 4201472;
         i += gridDim.x * 256) {
        if (i < 4194304) {
            const float* s; u16* d; int off;
            if (i < 1048576)      { s = x;  d = xb;    off = i; }
            else if (i < 1310720) { s = wq; d = wqkvb; off = i - 1048576; }
            else if (i < 1572864) { s = wk; d = wqkvb + 1048576; off = i - 1310720; }
            else if (i < 1835008) { s = wv; d = wqkvb + 2097152; off = i - 1572864; }
            else if (i < 2097152) { s = wo; d = wob;   off = i - 1835008; }
            else if (i < 3145728) { s = w1; d = w1b;   off = i - 2097152; }
            else                  { s = w2; d = w2b;   off = i - 3145728; }
            float4 v = reinterpret_cast<const float4*>(s)[off];
            ushort4 o;
            o.x = f2bf(v.x); o.y = f2bf(v.y); o.z = f2bf(v.z); o.w = f2bf(v.w);
            reinterpret_cast<ushort4*>(d)[off] = o;
        } else {
            int j = i - 4194304;                 // 0..7167
            if (j < 3 * D_) {
                float v = (j < D_) ? bq[j] : (j < 2 * D_) ? bk[j - D_] : bv[j - 2 * D_];
                bqkv[j] = v;
            } else {
                int k = j - 3 * D_;              // 0..4095
                mbias[k] = (mask[k] == 0) ? -1.44269504e9f : 0.0f;  // log2-domain
            }
        }
    }
}

// ---------------- 256x256 8-phase GEMM with optional split-K -----------------
// C[M,N] = A[M,K_chunk] @ B[N,K_chunk]^T (+ bias at z==0)
// blockIdx.z = K-chunk; Kc = K / gridDim.z. n-fastest tile mapping: co-XCD
// chunks share A-panels. EPI: 0 = bias->bf16; 1 = bf16 partial (z-offset
// buffer, bias z==0); 2 = bias+erf-GELU->bf16.
template <int EPI>
__global__ __launch_bounds__(512, 2) void gemm256_bt(const u16* __restrict__ A,
                                                     const u16* __restrict__ Bw,
                                                     const float* __restrict__ bias,
                                                     u16* __restrict__ Cb,
                                                     int N, int K) {
    __shared__ alignas(16) u16 sA[2][2][8192];   // [parity][half][128 rows x 64 k]
    __shared__ alignas(16) u16 sB[2][2][8192];
    const int tid = threadIdx.x;
    const int wid = tid >> 6, lane = tid & 63;
    const int lrow = lane & 15, lgrp = lane >> 4;
    const int wm = wid >> 2, wn = wid & 3;       // 2 x 4 wave grid
    const int z = blockIdx.z;
    const int Kc = K / gridDim.z;
    const int zbase = z * Kc;

    // bijective XCD swizzle (m204), then n-fastest: chunk shares A-panels
    const int nbx = gridDim.x, nby = gridDim.y;
    const int nwg = nbx * nby;
    const int orig = blockIdx.y * nbx + blockIdx.x;
    const int qd = nwg >> 3, rr = nwg & 7, xc = orig & 7, oi = orig >> 3;
    const int swz = (xc < rr ? xc * (qd + 1) : rr * (qd + 1) + (xc - rr) * qd) + oi;
    const int m0 = (swz / nby) * 256, n0 = (swz % nby) * 256;

    const u16* Ab = A + (size_t)m0 * K + zbase;
    const u16* Bb = Bw + (size_t)n0 * K + zbase;
    const int T = Kc >> 6;

    const int c0 = (wid * 2 + 0) * 64 + lane;
    const int c1 = (wid * 2 + 1) * 64 + lane;
    const int r0 = c0 >> 3, g0 = c0 & 7;
    const int r1 = c1 >> 3, g1 = c1 & 7;
    const size_t so0 = (size_t)r0 * K + (size_t)((g0 ^ (r0 & 7)) * 8);
    const size_t so1 = (size_t)r1 * K + (size_t)((g1 ^ (r1 & 7)) * 8);
    const int d0 = (wid * 2 + 0) * 512;
    const int d1 = (wid * 2 + 1) * 512;

    auto stageA = [&](int par, int half, int kt) {
        const u16* src = Ab + (size_t)(half * 128) * K + kt * 64;
        g2l16(src + so0, &sA[par][half][d0]);
        g2l16(src + so1, &sA[par][half][d1]);
    };
    auto stageB = [&](int par, int half, int kt) {
        const u16* src = Bb + (size_t)(half * 128) * K + kt * 64;
        g2l16(src + so0, &sB[par][half][d0]);
        g2l16(src + so1, &sB[par][half][d1]);
    };

    stageA(0, 0, 0); stageA(0, 1, 0);
    stageB(0, 0, 0); stageB(0, 1, 0);
    if (T > 1) { stageB(1, 0, 1); stageB(1, 1, 1); }
    asm volatile("s_waitcnt vmcnt(4)" ::: "memory");
    asm volatile("s_barrier" ::: "memory");

    floatx4 acc[8][4] = {};
    const int rbase = (wn & 1) * 64;
    const int bhalf = wn >> 1;

    for (int t = 0; t < T; t++) {
        const int par = t & 1;
        const char* baseA = (const char*)&sA[par][wm][0];
        const char* baseB = (const char*)&sB[par][bhalf][0];
        short8 bfr[4][2];
#pragma unroll
        for (int ph = 0; ph < 4; ph++) {
            if (ph == 0) {
#pragma unroll
                for (int nj = 0; nj < 4; nj++) {
                    int rb = rbase + nj * 16 + lrow;
#pragma unroll
                    for (int kk = 0; kk < 2; kk++) {
                        int off = rb * 128 + (((kk * 4 + lgrp) ^ (lrow & 7)) * 16);
                        bfr[nj][kk] = *reinterpret_cast<const short8*>(baseB + off);
                    }
                }
            }
            short8 af[2][2];
#pragma unroll
            for (int a = 0; a < 2; a++) {
                int ra = (2 * ph + a) * 16 + lrow;
#pragma unroll
                for (int kk = 0; kk < 2; kk++) {
                    int off = ra * 128 + (((kk * 4 + lgrp) ^ (lrow & 7)) * 16);
                    af[a][kk] = *reinterpret_cast<const short8*>(baseA + off);
                }
            }
            if (ph == 0) { if (t + 1 < T) stageA(par ^ 1, 0, t + 1); }
            if (ph == 1) { if (t + 1 < T) stageA(par ^ 1, 1, t + 1); }
            if (ph == 2) { if (t + 2 < T) stageB(par, 0, t + 2); }
            if (ph == 3) { if (t + 2 < T) stageB(par, 1, t + 2); }

            asm volatile("s_barrier" ::: "memory");
            asm volatile("s_waitcnt lgkmcnt(0)" ::: "memory");
            __builtin_amdgcn_sched_barrier(0);

            __builtin_amdgcn_s_setprio(1);
#pragma unroll
            for (int a = 0; a < 2; a++)
#pragma unroll
                for (int nj = 0; nj < 4; nj++) {
                    acc[2 * ph + a][nj] = __builtin_amdgcn_mfma_f32_16x16x32_bf16(
                        af[a][0], bfr[nj][0], acc[2 * ph + a][nj], 0, 0, 0);
                    acc[2 * ph + a][nj] = __builtin_amdgcn_mfma_f32_16x16x32_bf16(
                        af[a][1], bfr[nj][1], acc[2 * ph + a][nj], 0, 0, 0);
                }
            __builtin_amdgcn_s_setprio(0);

            if (ph == 3) {
                if (t >= T - 3) asm volatile("s_waitcnt vmcnt(0)" ::: "memory");
                else            asm volatile("s_waitcnt vmcnt(4)" ::: "memory");
            }
            asm volatile("s_barrier" ::: "memory");
        }
    }

    u16* Co = (EPI == 1) ? Cb + (size_t)z * M_ * N : Cb;
#pragma unroll
    for (int mi = 0; mi < 8; mi++) {
        int row = m0 + wm * 128 + mi * 16 + lgrp * 4;
#pragma unroll
        for (int nj = 0; nj < 4; nj++) {
            int col = n0 + wn * 64 + nj * 16 + lrow;
            float bc = (EPI != 1 || z == 0) ? bias[col] : 0.0f;
#pragma unroll
            for (int j = 0; j < 4; j++) {
                float v = acc[mi][nj][j] + bc;
                if (EPI == 2) v = 0.5f * v * (1.0f + erff(v * 0.70710678118654752f));
                Co[(size_t)(row + j) * N + col] = f2bf(v);
            }
        }
    }
}

// ---------------- flash attention (4 waves, 64 q-rows, 1024 blocks) ----------
// 40 KB LDS -> 4 blocks/CU (4 independent barrier groups per CU).
// Swapped QK^T (lane-local softmax), exp2 domain, early V tr-read, defer-max,
// double-buffered async K/V staging with counted vmcnt(4).
__global__ __launch_bounds__(256) void attn_kernel(const u16* __restrict__ QKV,
                                                   const float* __restrict__ mbias,
                                                   u16* __restrict__ O) {
    const int SD = 3 * D_;
    __shared__ alignas(16) u16 ktL[2][4096];   // [buf][64 kv][64 d] src-swizzled
    __shared__ alignas(16) u16 vtL[2][4096];   // [buf] tr-subtiled V
    __shared__ alignas(16) u16 pL[4][1024];    // per-wave P [16 q][64 kv] swizzled

    const int orig = blockIdx.y * gridDim.x + blockIdx.x;   // 1024 wgs
    const int swz = (orig & 7) * 128 + (orig >> 3);
    const int qt = swz & 31, bh = swz >> 5;
    const int b = bh >> 4, h = bh & 15;

    const int tid = threadIdx.x, wid = tid >> 6, lane = tid & 63;
    const int lrow = lane & 15, lgrp = lane >> 4;

    const u16* Qp = QKV + h * DK_;
    const u16* Kp = QKV + D_ + h * DK_;
    const u16* Vp = QKV + 2 * D_ + h * DK_;
    const float* mbrow = mbias + b * S_;

    const int qr = qt * 64 + wid * 16 + lrow;
    const u16* qrow = Qp + (size_t)(b * S_ + qr) * SD;
    short8 aq0 = *reinterpret_cast<const short8*>(qrow + lgrp * 8);
    short8 aq1 = *reinterpret_cast<const short8*>(qrow + 32 + lgrp * 8);

    // staging source pointers (r2/r3-verified pattern: 2 chunks/lane/buffer)
    const u16* kq[2];
    const u16* vq[2];
#pragma unroll
    for (int i = 0; i < 2; i++) {
        int s = wid * 2 + i;
        int q8 = s * 64 + lane;
        int krow = q8 >> 3, kcb = q8 & 7;
        kq[i] = Kp + (size_t)(b * S_ + krow) * SD + ((kcb ^ (krow & 7)) * 8);
        int o = s * 512 + lane * 8;
        int vk = ((o >> 6) & 7) * 8 + ((o >> 9) & 1) * 4 + ((o >> 4) & 3);
        int vd = (o >> 10) * 16 + (o & 8);
        vq[i] = Vp + (size_t)(b * S_ + vk) * SD + vd;
    }

    auto issue = [&](int bufIdx) {
        u16* kb_ = ktL[bufIdx];
        u16* vb_ = vtL[bufIdx];
#pragma unroll
        for (int i = 0; i < 2; i++) {
            int s = wid * 2 + i;
            g2l16(kq[i], kb_ + s * 512);
            g2l16(vq[i], vb_ + s * 512);
            kq[i] += 64 * SD;
            vq[i] += 64 * SD;
        }
    };

    floatx4 accO[4] = {};
    float mrun = -1e30f, lrun = 0.f;
    const float SC2 = 0.18033688011112042f;    // 0.125 * log2(e)

    issue(0);
    int cur = 0;
    for (int t = 0; t < S_ / 64; t++) {
        const int kv0 = t * 64;
        if (t < S_ / 64 - 1) {
            issue(cur ^ 1);
            asm volatile("s_waitcnt vmcnt(4)" ::: "memory");
        } else {
            asm volatile("s_waitcnt vmcnt(0)" ::: "memory");
        }
        __builtin_amdgcn_s_barrier();
        asm volatile("" ::: "memory");

        const u16* ktc = ktL[cur];
        const unsigned vva = lds_off(vtL[cur]) + lane * 8;

        float4 mb[4];
#pragma unroll
        for (int ni = 0; ni < 4; ni++)
            mb[ni] = *reinterpret_cast<const float4*>(mbrow + kv0 + ni * 16 + lgrp * 4);

        // ---- swapped QK^T: S^T[kv][q] ----
        floatx4 st[4];
        __builtin_amdgcn_s_setprio(1);
#pragma unroll
        for (int ni = 0; ni < 4; ni++) {
            int row = ni * 16 + lrow;
            int off0 = (row * 128 + lgrp * 16) ^ ((lrow & 7) << 4);
            int off1 = (row * 128 + 64 + lgrp * 16) ^ ((lrow & 7) << 4);
            short8 bk0 = *reinterpret_cast<const short8*>((const char*)ktc + off0);
            short8 bk1 = *reinterpret_cast<const short8*>((const char*)ktc + off1);
            floatx4 z = {0.f, 0.f, 0.f, 0.f};
            z = __builtin_amdgcn_mfma_f32_16x16x32_bf16(bk0, aq0, z, 0, 0, 0);
            z = __builtin_amdgcn_mfma_f32_16x16x32_bf16(bk1, aq1, z, 0, 0, 0);
            st[ni] = z;
        }
        __builtin_amdgcn_s_setprio(0);

        // ---- early V tr-read issue: latency hides under softmax ----
        bf16x4 vt0[4], vt1[4], vt2[4], vt3[4];
#pragma unroll
        for (int nd = 0; nd < 4; nd++) {
            unsigned a = vva + nd * 2048;
            TRB16(vt0[nd], a, 0);
            TRB16(vt1[nd], a, 1024);
            TRB16(vt2[nd], a, 512);
            TRB16(vt3[nd], a, 1536);
        }

        // ---- softmax (log2 domain, lane-local) ----
        float pm[4][4];
#pragma unroll
        for (int ni = 0; ni < 4; ni++) {
            const float* mbp = reinterpret_cast<const float*>(&mb[ni]);
#pragma unroll
            for (int j = 0; j < 4; j++)
                pm[ni][j] = fmaf(st[ni][j], SC2, mbp[j]);
        }
        float pmax = pm[0][0];
#pragma unroll
        for (int ni = 0; ni < 4; ni++)
#pragma unroll
            for (int j = 0; j < 4; j++) pmax = fmaxf(pmax, pm[ni][j]);
        pmax = fmaxf(pmax, __shfl_xor(pmax, 16, 64));
        pmax = fmaxf(pmax, __shfl_xor(pmax, 32, 64));

        bool upd = !__all(pmax - mrun <= 11.5f);
        float fac = 1.0f;
        if (upd) {
            float mn = fmaxf(mrun, pmax);
            fac = exp2_fast(mrun - mn);
            mrun = mn;
        }

        float p[4][4];
        float s = 0.f;
#pragma unroll
        for (int ni = 0; ni < 4; ni++)
#pragma unroll
            for (int j = 0; j < 4; j++) {
                float e = exp2_fast(pm[ni][j] - mrun);
                p[ni][j] = e;
                s += e;
            }
        s += __shfl_xor(s, 16, 64);
        s += __shfl_xor(s, 32, 64);
        lrun = lrun * fac + s;

        // ---- P -> LDS [q=lrow][kv] XOR-swizzled ----
#pragma unroll
        for (int ni = 0; ni < 4; ni++) {
            bf16x4 pw;
#pragma unroll
            for (int j = 0; j < 4; j++) pw[j] = (short)f2bf_fast(p[ni][j]);
            unsigned woff = (unsigned)((lrow * 128 + ni * 32 + lgrp * 8) ^ ((lrow & 7) << 4));
            *reinterpret_cast<bf16x4*>((char*)pL[wid] + woff) = pw;
        }

        if (upd) {
            float f0 = __shfl(fac, lgrp * 4 + 0, 64);
            float f1 = __shfl(fac, lgrp * 4 + 1, 64);
            float f2 = __shfl(fac, lgrp * 4 + 2, 64);
            float f3 = __shfl(fac, lgrp * 4 + 3, 64);
#pragma unroll
            for (int nd = 0; nd < 4; nd++) {
                floatx4 tt = accO[nd];
                tt[0] *= f0; tt[1] *= f1; tt[2] *= f2; tt[3] *= f3;
                accO[nd] = tt;
            }
        }

        asm volatile("s_waitcnt lgkmcnt(0)" ::: "memory");
        __builtin_amdgcn_sched_barrier(0);

        unsigned ra0 = (unsigned)((lrow * 128 + lgrp * 16) ^ ((lrow & 7) << 4));
        unsigned ra1 = (unsigned)((lrow * 128 + 64 + lgrp * 16) ^ ((lrow & 7) << 4));
        short8 ap0 = *reinterpret_cast<const short8*>((const char*)pL[wid] + ra0);
        short8 ap1 = *reinterpret_cast<const short8*>((const char*)pL[wid] + ra1);

        __builtin_amdgcn_s_setprio(1);
#pragma unroll
        for (int nd = 0; nd < 4; nd++) {
            short8 bv0 = __builtin_shufflevector(vt0[nd], vt1[nd], 0, 1, 2, 3, 4, 5, 6, 7);
            short8 bv1 = __builtin_shufflevector(vt2[nd], vt3[nd], 0, 1, 2, 3, 4, 5, 6, 7);
            accO[nd] = __builtin_amdgcn_mfma_f32_16x16x32_bf16(ap0, bv0, accO[nd], 0, 0, 0);
            accO[nd] = __builtin_amdgcn_mfma_f32_16x16x32_bf16(ap1, bv1, accO[nd], 0, 0, 0);
        }
        __builtin_amdgcn_s_setprio(0);

        asm volatile("" ::: "memory");
        __builtin_amdgcn_s_barrier();
        cur ^= 1;
    }

    float linv = 1.0f / lrun;
    float li[4];
#pragma unroll
    for (int j = 0; j < 4; j++) li[j] = __shfl(linv, lgrp * 4 + j, 64);
#pragma unroll
    for (int nd = 0; nd < 4; nd++)
#pragma unroll
        for (int j = 0; j < 4; j++) {
            int r = lgrp * 4 + j;
            float v = accO[nd][j] * li[j];
            O[(size_t)(b * S_ + qt * 64 + wid * 16 + r) * D_ + h * DK_ + nd * 16 + lrow] =
                f2bf_fast(v);
        }
}

// --------- residual(+4 bf16 split-K partials) + LayerNorm --------------------
// torch semantics: ddof=1, eps OUTSIDE sqrt. v = X + sum(bf16 partials)
__global__ __launch_bounds__(256) void ln_bf(const float* __restrict__ X,
                                             const u16* __restrict__ R0,
                                             const u16* __restrict__ R1,
                                             const u16* __restrict__ R2,
                                             const u16* __restrict__ R3,
                                             const float* __restrict__ gam,
                                             const float* __restrict__ bet,
                                             float* __restrict__ outf,
                                             u16* __restrict__ outb) {
    __shared__ float ws1[4], ws2[4];
    const int row = blockIdx.x, tid = threadIdx.x;
    const size_t ro = (size_t)row * D_;
    float4 v = reinterpret_cast<const float4*>(X + ro)[tid];
    {
        ushort4 r = reinterpret_cast<const ushort4*>(R0 + ro)[tid];
        v.x += b2f(r.x); v.y += b2f(r.y); v.z += b2f(r.z); v.w += b2f(r.w);
    }
    {
        ushort4 r = reinterpret_cast<const ushort4*>(R1 + ro)[tid];
        v.x += b2f(r.x); v.y += b2f(r.y); v.z += b2f(r.z); v.w += b2f(r.w);
    }
    {
        ushort4 r = reinterpret_cast<const ushort4*>(R2 + ro)[tid];
        v.x += b2f(r.x); v.y += b2f(r.y); v.z += b2f(r.z); v.w += b2f(r.w);
    }
    {
        ushort4 r = reinterpret_cast<const ushort4*>(R3 + ro)[tid];
        v.x += b2f(r.x); v.y += b2f(r.y); v.z += b2f(r.z); v.w += b2f(r.w);
    }

    float s = v.x + v.y + v.z + v.w;
#pragma unroll
    for (int m = 32; m >= 1; m >>= 1) s += __shfl_xor(s, m, 64);
    if ((tid & 63) == 0) ws1[tid >> 6] = s;
    __syncthreads();
    float mean = (ws1[0] + ws1[1] + ws1[2] + ws1[3]) * (1.f / D_);

    float4 d; d.x = v.x - mean; d.y = v.y - mean; d.z = v.z - mean; d.w = v.w - mean;
    float q = d.x * d.x + d.y * d.y + d.z * d.z + d.w * d.w;
#pragma unroll
    for (int m = 32; m >= 1; m >>= 1) q += __shfl_xor(q, m, 64);
    if ((tid & 63) == 0) ws2[tid >> 6] = q;
    __syncthreads();
    float var = (ws2[0] + ws2[1] + ws2[2] + ws2[3]) * (1.f / (D_ - 1));
    float inv = 1.f / (sqrtf(var) + 1e-6f);

    const float4 g = reinterpret_cast<const float4*>(gam)[tid];
    const float4 bb = reinterpret_cast<const float4*>(bet)[tid];
    float4 o;
    o.x = g.x * d.x * inv + bb.x;
    o.y = g.y * d.y * inv + bb.y;
    o.z = g.z * d.z * inv + bb.z;
    o.w = g.w * d.w * inv + bb.w;
    if (outf) reinterpret_cast<float4*>(outf + ro)[tid] = o;
    if (outb) {
        ushort4 ob;
        ob.x = f2bf(o.x); ob.y = f2bf(o.y); ob.z = f2bf(o.z); ob.w = f2bf(o.w);
        reinterpret_cast<ushort4*>(outb + ro)[tid] = ob;
    }
}

// ---------------- launcher ----------------
extern "C" void kernel_launch(void* const* d_in, const int* in_sizes, int n_in,
                              void* d_out, int out_size, void* d_ws, size_t ws_size,
                              hipStream_t stream) {
    const float* x    = (const float*)d_in[0];
    const int*   mask = (const int*)d_in[1];
    const float* wq   = (const float*)d_in[2];
    const float* bq   = (const float*)d_in[3];
    const float* wk   = (const float*)d_in[4];
    const float* bk   = (const float*)d_in[5];
    const float* wv   = (const float*)d_in[6];
    const float* bv   = (const float*)d_in[7];
    const float* wo   = (const float*)d_in[8];
    const float* bo   = (const float*)d_in[9];
    const float* g1   = (const float*)d_in[10];
    const float* b1   = (const float*)d_in[11];
    const float* g2   = (const float*)d_in[12];
    const float* b2   = (const float*)d_in[13];
    const float* w1   = (const float*)d_in[14];
    const float* bf1  = (const float*)d_in[15];
    const float* w2   = (const float*)d_in[16];
    const float* bf2  = (const float*)d_in[17];
    float* out = (float*)d_out;

    char* ws = (char*)d_ws;
    const size_t MB = 1u << 20;
    // Transient region (0..72 MB):
    //   xb@0 (8, dead after QKV), wqkvb@8 (6, dead after QKV),
    //   qkvb@14 (24, dead after attn), cvb@64 (8, dead after proj),
    //   pp@0 (32, bf16 proj partials; dead after LN1),
    //   qpart@0 (32, bf16 FFN2 partials; dead after LN2)
    u16*   xb    = (u16*)  (ws + 0 * MB);
    u16*   wqkvb = (u16*)  (ws + 8 * MB);
    u16*   qkvb  = (u16*)  (ws + 14 * MB);
    u16*   cvb   = (u16*)  (ws + 64 * MB);
    u16*   pp    = (u16*)  (ws + 0 * MB);
    u16*   qpart = (u16*)  (ws + 0 * MB);
    // Persistent region (72..147 MB):
    u16*   wob   = (u16*)  (ws + 72 * MB);
    u16*   w1b   = (u16*)  (ws + 74 * MB);
    u16*   w2b   = (u16*)  (ws + 82 * MB);
    float* bqkv  = (float*)(ws + 90 * MB);
    float* mbias = (float*)(ws + 90 * MB + 65536);
    float* hdf   = (float*)(ws + 91 * MB);
    u16*   hdb   = (u16*)  (ws + 107 * MB);
    u16*   ff1b  = (u16*)  (ws + 115 * MB);   // ends 147 MB

    cvt_all<<<2048, 256, 0, stream>>>(x, wq, wk, wv, wo, w1, w2,
                                      bq, bk, bv, mask,
                                      xb, wqkvb, wob, w1b, w2b, bqkv, mbias);

    // fused QKV projection: [4096,3072,1024] on 256x256 8-phase
    gemm256_bt<0><<<dim3(M_ / 256, 3 * D_ / 256, 1), 512, 0, stream>>>(
        xb, wqkvb, bqkv, qkvb, 3 * D_, D_);

    // attention: 4 waves, 64 q-rows per block, 1024 blocks (4 blocks/CU)
    attn_kernel<<<dim3(S_ / 64, B_ * H_), 256, 0, stream>>>(qkvb, mbias, cvb);

    // output projection: [4096,1024,1024] split-K4 -> bf16 partials pp[0..3]
    gemm256_bt<1><<<dim3(M_ / 256, D_ / 256, 4), 512, 0, stream>>>(
        cvb, wob, bo, pp, D_, D_);

    // residual + LN1: hd = LN(x + pp0..pp3)
    ln_bf<<<M_, 256, 0, stream>>>(x, pp, pp + (size_t)M_ * D_,
                                  pp + 2 * (size_t)M_ * D_,
                                  pp + 3 * (size_t)M_ * D_,
                                  g1, b1, hdf, hdb);

    // FFN1 + GELU: [4096,4096,1024] on 256x256 8-phase
    gemm256_bt<2><<<dim3(M_ / 256, DFF_ / 256, 1), 512, 0, stream>>>(
        hdb, w1b, bf1, ff1b, DFF_, D_);

    // FFN2: [4096,1024,4096] split-K4 -> bf16 partials qpart[0..3]
    gemm256_bt<1><<<dim3(M_ / 256, D_ / 256, 4), 512, 0, stream>>>(
        ff1b, w2b, bf2, qpart, D_, DFF_);

    // residual + LN2 -> out = LN(hdf + q0..q3)
    ln_bf<<<M_, 256, 0, stream>>>(hdf, qpart, qpart + (size_t)M_ * D_,
                                  qpart + 2 * (size_t)M_ * D_,
                                  qpart + 3 * (size_t)M_ * D_,
                                  g2, b2, out, nullptr);
}

// Round 11
// 374.170 us; speedup vs baseline: 1.0906x; 1.0906x over previous
//
#include <hip/hip_runtime.h>
#include <hip/hip_bf16.h>

// ---------------- constants (problem shape) ----------------
#define B_   2
#define S_   2048
#define D_   1024
#define H_   16
#define DK_  64
#define DFF_ 4096
#define M_   (B_*S_)   // 4096 rows

typedef unsigned short u16;
typedef __attribute__((ext_vector_type(8))) short short8;
typedef __attribute__((ext_vector_type(4))) short bf16x4;
typedef __attribute__((ext_vector_type(4))) float floatx4;

__device__ __forceinline__ u16 f2bf(float f) {
    union { float f; unsigned u; } v; v.f = f;
    unsigned r = v.u + 0x7fffu + ((v.u >> 16) & 1u);
    return (u16)(r >> 16);
}
__device__ __forceinline__ u16 f2bf_fast(float f) {
    __hip_bfloat16 h = __float2bfloat16(f);
    return *reinterpret_cast<u16*>(&h);
}
__device__ __forceinline__ float b2f(u16 u) {
    union { unsigned u; float f; } v; v.u = ((unsigned)u) << 16; return v.f;
}
__device__ __forceinline__ float exp2_fast(float f) {
    return __builtin_amdgcn_exp2f(f);
}
__device__ __forceinline__ void g2l16(const u16* g, u16* l) {
    __builtin_amdgcn_global_load_lds((const __attribute__((address_space(1))) void*)g,
                                     (__attribute__((address_space(3))) void*)l,
                                     16, 0, 0);
}
__device__ __forceinline__ unsigned lds_off(const void* p) {
    return (unsigned)(unsigned long long)p;
}

#define TRB16(dst, va, IMM)                                                    \
    asm volatile("ds_read_b64_tr_b16 %0, %1 offset:" #IMM                      \
                 : "=v"(dst) : "v"(va))

// ------- fused fp32->bf16 conversion of x + weights, bias concat, mbias -----
__global__ __launch_bounds__(256) void cvt_all(
    const float* __restrict__ x,  const float* __restrict__ wq,
    const float* __restrict__ wk, const float* __restrict__ wv,
    const float* __restrict__ wo, const float* __restrict__ w1,
    const float* __restrict__ w2,
    const float* __restrict__ bq, const float* __restrict__ bk,
    const float* __restrict__ bv, const int* __restrict__ mask,
    u16* __restrict__ xb, u16* __restrict__ wqkvb, u16* __restrict__ wob,
    u16* __restrict__ w1b, u16* __restrict__ w2b,
    float* __restrict__ bqkv, float* __restrict__ mbias) {
    for (int i = blockIdx.x * 256 + threadIdx.x; i < 4201472;
         i += gridDim.x * 256) {
        if (i < 4194304) {
            const float* s; u16* d; int off;
            if (i < 1048576)      { s = x;  d = xb;    off = i; }
            else if (i < 1310720) { s = wq; d = wqkvb; off = i - 1048576; }
            else if (i < 1572864) { s = wk; d = wqkvb + 1048576; off = i - 1310720; }
            else if (i < 1835008) { s = wv; d = wqkvb + 2097152; off = i - 1572864; }
            else if (i < 2097152) { s = wo; d = wob;   off = i - 1835008; }
            else if (i < 3145728) { s = w1; d = w1b;   off = i - 2097152; }
            else                  { s = w2; d = w2b;   off = i - 3145728; }
            float4 v = reinterpret_cast<const float4*>(s)[off];
            ushort4 o;
            o.x = f2bf(v.x); o.y = f2bf(v.y); o.z = f2bf(v.z); o.w = f2bf(v.w);
            reinterpret_cast<ushort4*>(d)[off] = o;
        } else {
            int j = i - 4194304;                 // 0..7167
            if (j < 3 * D_) {
                float v = (j < D_) ? bq[j] : (j < 2 * D_) ? bk[j - D_] : bv[j - 2 * D_];
                bqkv[j] = v;
            } else {
                int k = j - 3 * D_;              // 0..4095
                mbias[k] = (mask[k] == 0) ? -1.44269504e9f : 0.0f;  // log2-domain
            }
        }
    }
}

// ---------------- 256x256 8-phase GEMM with optional split-K -----------------
// C[M,N] = A[M,K_chunk] @ B[N,K_chunk]^T (+ bias at z==0)
// blockIdx.z = K-chunk; Kc = K / gridDim.z. n-fastest tile mapping: co-XCD
// chunks share A-panels. EPI: 0 = bias->bf16; 1 = bf16 partial (z-offset
// buffer, bias z==0); 2 = bias+erf-GELU->bf16.
template <int EPI>
__global__ __launch_bounds__(512, 2) void gemm256_bt(const u16* __restrict__ A,
                                                     const u16* __restrict__ Bw,
                                                     const float* __restrict__ bias,
                                                     u16* __restrict__ Cb,
                                                     int N, int K) {
    __shared__ alignas(16) u16 sA[2][2][8192];   // [parity][half][128 rows x 64 k]
    __shared__ alignas(16) u16 sB[2][2][8192];
    const int tid = threadIdx.x;
    const int wid = tid >> 6, lane = tid & 63;
    const int lrow = lane & 15, lgrp = lane >> 4;
    const int wm = wid >> 2, wn = wid & 3;       // 2 x 4 wave grid
    const int z = blockIdx.z;
    const int Kc = K / gridDim.z;
    const int zbase = z * Kc;

    // bijective XCD swizzle (m204), then n-fastest: chunk shares A-panels
    const int nbx = gridDim.x, nby = gridDim.y;
    const int nwg = nbx * nby;
    const int orig = blockIdx.y * nbx + blockIdx.x;
    const int qd = nwg >> 3, rr = nwg & 7, xc = orig & 7, oi = orig >> 3;
    const int swz = (xc < rr ? xc * (qd + 1) : rr * (qd + 1) + (xc - rr) * qd) + oi;
    const int m0 = (swz / nby) * 256, n0 = (swz % nby) * 256;

    const u16* Ab = A + (size_t)m0 * K + zbase;
    const u16* Bb = Bw + (size_t)n0 * K + zbase;
    const int T = Kc >> 6;

    const int c0 = (wid * 2 + 0) * 64 + lane;
    const int c1 = (wid * 2 + 1) * 64 + lane;
    const int r0 = c0 >> 3, g0 = c0 & 7;
    const int r1 = c1 >> 3, g1 = c1 & 7;
    const size_t so0 = (size_t)r0 * K + (size_t)((g0 ^ (r0 & 7)) * 8);
    const size_t so1 = (size_t)r1 * K + (size_t)((g1 ^ (r1 & 7)) * 8);
    const int d0 = (wid * 2 + 0) * 512;
    const int d1 = (wid * 2 + 1) * 512;

    auto stageA = [&](int par, int half, int kt) {
        const u16* src = Ab + (size_t)(half * 128) * K + kt * 64;
        g2l16(src + so0, &sA[par][half][d0]);
        g2l16(src + so1, &sA[par][half][d1]);
    };
    auto stageB = [&](int par, int half, int kt) {
        const u16* src = Bb + (size_t)(half * 128) * K + kt * 64;
        g2l16(src + so0, &sB[par][half][d0]);
        g2l16(src + so1, &sB[par][half][d1]);
    };

    stageA(0, 0, 0); stageA(0, 1, 0);
    stageB(0, 0, 0); stageB(0, 1, 0);
    if (T > 1) { stageB(1, 0, 1); stageB(1, 1, 1); }
    asm volatile("s_waitcnt vmcnt(4)" ::: "memory");
    asm volatile("s_barrier" ::: "memory");

    floatx4 acc[8][4] = {};
    const int rbase = (wn & 1) * 64;
    const int bhalf = wn >> 1;

    for (int t = 0; t < T; t++) {
        const int par = t & 1;
        const char* baseA = (const char*)&sA[par][wm][0];
        const char* baseB = (const char*)&sB[par][bhalf][0];
        short8 bfr[4][2];
#pragma unroll
        for (int ph = 0; ph < 4; ph++) {
            if (ph == 0) {
#pragma unroll
                for (int nj = 0; nj < 4; nj++) {
                    int rb = rbase + nj * 16 + lrow;
#pragma unroll
                    for (int kk = 0; kk < 2; kk++) {
                        int off = rb * 128 + (((kk * 4 + lgrp) ^ (lrow & 7)) * 16);
                        bfr[nj][kk] = *reinterpret_cast<const short8*>(baseB + off);
                    }
                }
            }
            short8 af[2][2];
#pragma unroll
            for (int a = 0; a < 2; a++) {
                int ra = (2 * ph + a) * 16 + lrow;
#pragma unroll
                for (int kk = 0; kk < 2; kk++) {
                    int off = ra * 128 + (((kk * 4 + lgrp) ^ (lrow & 7)) * 16);
                    af[a][kk] = *reinterpret_cast<const short8*>(baseA + off);
                }
            }
            if (ph == 0) { if (t + 1 < T) stageA(par ^ 1, 0, t + 1); }
            if (ph == 1) { if (t + 1 < T) stageA(par ^ 1, 1, t + 1); }
            if (ph == 2) { if (t + 2 < T) stageB(par, 0, t + 2); }
            if (ph == 3) { if (t + 2 < T) stageB(par, 1, t + 2); }

            asm volatile("s_barrier" ::: "memory");
            asm volatile("s_waitcnt lgkmcnt(0)" ::: "memory");
            __builtin_amdgcn_sched_barrier(0);

            __builtin_amdgcn_s_setprio(1);
#pragma unroll
            for (int a = 0; a < 2; a++)
#pragma unroll
                for (int nj = 0; nj < 4; nj++) {
                    acc[2 * ph + a][nj] = __builtin_amdgcn_mfma_f32_16x16x32_bf16(
                        af[a][0], bfr[nj][0], acc[2 * ph + a][nj], 0, 0, 0);
                    acc[2 * ph + a][nj] = __builtin_amdgcn_mfma_f32_16x16x32_bf16(
                        af[a][1], bfr[nj][1], acc[2 * ph + a][nj], 0, 0, 0);
                }
            __builtin_amdgcn_s_setprio(0);

            if (ph == 3) {
                if (t >= T - 3) asm volatile("s_waitcnt vmcnt(0)" ::: "memory");
                else            asm volatile("s_waitcnt vmcnt(4)" ::: "memory");
            }
            asm volatile("s_barrier" ::: "memory");
        }
    }

    u16* Co = (EPI == 1) ? Cb + (size_t)z * M_ * N : Cb;
#pragma unroll
    for (int mi = 0; mi < 8; mi++) {
        int row = m0 + wm * 128 + mi * 16 + lgrp * 4;
#pragma unroll
        for (int nj = 0; nj < 4; nj++) {
            int col = n0 + wn * 64 + nj * 16 + lrow;
            float bc = (EPI != 1 || z == 0) ? bias[col] : 0.0f;
#pragma unroll
            for (int j = 0; j < 4; j++) {
                float v = acc[mi][nj][j] + bc;
                if (EPI == 2) v = 0.5f * v * (1.0f + erff(v * 0.70710678118654752f));
                Co[(size_t)(row + j) * N + col] = f2bf(v);
            }
        }
    }
}

// ---------------- flash attention (8 waves, 128 q-rows, 512 blocks) ----------
// Measured-best variant (round 9: 71.3 us). Swapped QK^T (lane-local softmax),
// exp2 domain, early V tr-read, defer-max, double-buffered async K/V staging
// with counted vmcnt(2).
__global__ __launch_bounds__(512) void attn_kernel(const u16* __restrict__ QKV,
                                                   const float* __restrict__ mbias,
                                                   u16* __restrict__ O) {
    const int SD = 3 * D_;
    __shared__ alignas(16) u16 ktL[2][4096];   // [buf][64 kv][64 d] src-swizzled
    __shared__ alignas(16) u16 vtL[2][4096];   // [buf] tr-subtiled V
    __shared__ alignas(16) u16 pL[8][1024];    // per-wave P [16 q][64 kv] swizzled

    const int orig = blockIdx.y * gridDim.x + blockIdx.x;   // 512 wgs
    const int swz = (orig & 7) * 64 + (orig >> 3);
    const int qt = swz & 15, bh = swz >> 4;
    const int b = bh >> 4, h = bh & 15;

    const int tid = threadIdx.x, wid = tid >> 6, lane = tid & 63;
    const int lrow = lane & 15, lgrp = lane >> 4;

    const u16* Qp = QKV + h * DK_;
    const u16* Kp = QKV + D_ + h * DK_;
    const u16* Vp = QKV + 2 * D_ + h * DK_;
    const float* mbrow = mbias + b * S_;

    const int qr = qt * 128 + wid * 16 + lrow;
    const u16* qrow = Qp + (size_t)(b * S_ + qr) * SD;
    short8 aq0 = *reinterpret_cast<const short8*>(qrow + lgrp * 8);
    short8 aq1 = *reinterpret_cast<const short8*>(qrow + 32 + lgrp * 8);

    const int q8 = wid * 64 + lane;
    const int krow = q8 >> 3, kcb = q8 & 7;
    const u16* kq = Kp + (size_t)(b * S_ + krow) * SD + ((kcb ^ (krow & 7)) * 8);
    const int ov = wid * 512 + lane * 8;
    const int vk = ((ov >> 6) & 7) * 8 + ((ov >> 9) & 1) * 4 + ((ov >> 4) & 3);
    const int vd = (ov >> 10) * 16 + (ov & 8);
    const u16* vq = Vp + (size_t)(b * S_ + vk) * SD + vd;

    auto issue = [&](int bufIdx) {
        g2l16(kq, &ktL[bufIdx][wid * 512]);
        g2l16(vq, &vtL[bufIdx][wid * 512]);
        kq += 64 * SD;
        vq += 64 * SD;
    };

    floatx4 accO[4] = {};
    float mrun = -1e30f, lrun = 0.f;
    const float SC2 = 0.18033688011112042f;    // 0.125 * log2(e)

    issue(0);
    int cur = 0;
    for (int t = 0; t < S_ / 64; t++) {
        const int kv0 = t * 64;
        if (t < S_ / 64 - 1) {
            issue(cur ^ 1);
            asm volatile("s_waitcnt vmcnt(2)" ::: "memory");
        } else {
            asm volatile("s_waitcnt vmcnt(0)" ::: "memory");
        }
        __builtin_amdgcn_s_barrier();
        asm volatile("" ::: "memory");

        const u16* ktc = ktL[cur];
        const unsigned vva = lds_off(vtL[cur]) + lane * 8;

        float4 mb[4];
#pragma unroll
        for (int ni = 0; ni < 4; ni++)
            mb[ni] = *reinterpret_cast<const float4*>(mbrow + kv0 + ni * 16 + lgrp * 4);

        // ---- swapped QK^T: S^T[kv][q] ----
        floatx4 st[4];
        __builtin_amdgcn_s_setprio(1);
#pragma unroll
        for (int ni = 0; ni < 4; ni++) {
            int row = ni * 16 + lrow;
            int off0 = (row * 128 + lgrp * 16) ^ ((lrow & 7) << 4);
            int off1 = (row * 128 + 64 + lgrp * 16) ^ ((lrow & 7) << 4);
            short8 bk0 = *reinterpret_cast<const short8*>((const char*)ktc + off0);
            short8 bk1 = *reinterpret_cast<const short8*>((const char*)ktc + off1);
            floatx4 z = {0.f, 0.f, 0.f, 0.f};
            z = __builtin_amdgcn_mfma_f32_16x16x32_bf16(bk0, aq0, z, 0, 0, 0);
            z = __builtin_amdgcn_mfma_f32_16x16x32_bf16(bk1, aq1, z, 0, 0, 0);
            st[ni] = z;
        }
        __builtin_amdgcn_s_setprio(0);

        // ---- early V tr-read issue: latency hides under softmax ----
        bf16x4 vt0[4], vt1[4], vt2[4], vt3[4];
#pragma unroll
        for (int nd = 0; nd < 4; nd++) {
            unsigned a = vva + nd * 2048;
            TRB16(vt0[nd], a, 0);
            TRB16(vt1[nd], a, 1024);
            TRB16(vt2[nd], a, 512);
            TRB16(vt3[nd], a, 1536);
        }

        // ---- softmax (log2 domain, lane-local) ----
        float pm[4][4];
#pragma unroll
        for (int ni = 0; ni < 4; ni++) {
            const float* mbp = reinterpret_cast<const float*>(&mb[ni]);
#pragma unroll
            for (int j = 0; j < 4; j++)
                pm[ni][j] = fmaf(st[ni][j], SC2, mbp[j]);
        }
        float pmax = pm[0][0];
#pragma unroll
        for (int ni = 0; ni < 4; ni++)
#pragma unroll
            for (int j = 0; j < 4; j++) pmax = fmaxf(pmax, pm[ni][j]);
        pmax = fmaxf(pmax, __shfl_xor(pmax, 16, 64));
        pmax = fmaxf(pmax, __shfl_xor(pmax, 32, 64));

        bool upd = !__all(pmax - mrun <= 11.5f);
        float fac = 1.0f;
        if (upd) {
            float mn = fmaxf(mrun, pmax);
            fac = exp2_fast(mrun - mn);
            mrun = mn;
        }

        float p[4][4];
        float s = 0.f;
#pragma unroll
        for (int ni = 0; ni < 4; ni++)
#pragma unroll
            for (int j = 0; j < 4; j++) {
                float e = exp2_fast(pm[ni][j] - mrun);
                p[ni][j] = e;
                s += e;
            }
        s += __shfl_xor(s, 16, 64);
        s += __shfl_xor(s, 32, 64);
        lrun = lrun * fac + s;

        // ---- P -> LDS [q=lrow][kv] XOR-swizzled ----
#pragma unroll
        for (int ni = 0; ni < 4; ni++) {
            bf16x4 pw;
#pragma unroll
            for (int j = 0; j < 4; j++) pw[j] = (short)f2bf_fast(p[ni][j]);
            unsigned woff = (unsigned)((lrow * 128 + ni * 32 + lgrp * 8) ^ ((lrow & 7) << 4));
            *reinterpret_cast<bf16x4*>((char*)pL[wid] + woff) = pw;
        }

        if (upd) {
            float f0 = __shfl(fac, lgrp * 4 + 0, 64);
            float f1 = __shfl(fac, lgrp * 4 + 1, 64);
            float f2 = __shfl(fac, lgrp * 4 + 2, 64);
            float f3 = __shfl(fac, lgrp * 4 + 3, 64);
#pragma unroll
            for (int nd = 0; nd < 4; nd++) {
                floatx4 tt = accO[nd];
                tt[0] *= f0; tt[1] *= f1; tt[2] *= f2; tt[3] *= f3;
                accO[nd] = tt;
            }
        }

        asm volatile("s_waitcnt lgkmcnt(0)" ::: "memory");
        __builtin_amdgcn_sched_barrier(0);

        unsigned ra0 = (unsigned)((lrow * 128 + lgrp * 16) ^ ((lrow & 7) << 4));
        unsigned ra1 = (unsigned)((lrow * 128 + 64 + lgrp * 16) ^ ((lrow & 7) << 4));
        short8 ap0 = *reinterpret_cast<const short8*>((const char*)pL[wid] + ra0);
        short8 ap1 = *reinterpret_cast<const short8*>((const char*)pL[wid] + ra1);

        __builtin_amdgcn_s_setprio(1);
#pragma unroll
        for (int nd = 0; nd < 4; nd++) {
            short8 bv0 = __builtin_shufflevector(vt0[nd], vt1[nd], 0, 1, 2, 3, 4, 5, 6, 7);
            short8 bv1 = __builtin_shufflevector(vt2[nd], vt3[nd], 0, 1, 2, 3, 4, 5, 6, 7);
            accO[nd] = __builtin_amdgcn_mfma_f32_16x16x32_bf16(ap0, bv0, accO[nd], 0, 0, 0);
            accO[nd] = __builtin_amdgcn_mfma_f32_16x16x32_bf16(ap1, bv1, accO[nd], 0, 0, 0);
        }
        __builtin_amdgcn_s_setprio(0);

        asm volatile("" ::: "memory");
        __builtin_amdgcn_s_barrier();
        cur ^= 1;
    }

    float linv = 1.0f / lrun;
    float li[4];
#pragma unroll
    for (int j = 0; j < 4; j++) li[j] = __shfl(linv, lgrp * 4 + j, 64);
#pragma unroll
    for (int nd = 0; nd < 4; nd++)
#pragma unroll
        for (int j = 0; j < 4; j++) {
            int r = lgrp * 4 + j;
            float v = accO[nd][j] * li[j];
            O[(size_t)(b * S_ + qt * 128 + wid * 16 + r) * D_ + h * DK_ + nd * 16 + lrow] =
                f2bf_fast(v);
        }
}

// --------- residual(+4 bf16 split-K partials) + LayerNorm --------------------
// torch semantics: ddof=1, eps OUTSIDE sqrt. v = X + sum(bf16 partials)
__global__ __launch_bounds__(256) void ln_bf(const float* __restrict__ X,
                                             const u16* __restrict__ R0,
                                             const u16* __restrict__ R1,
                                             const u16* __restrict__ R2,
                                             const u16* __restrict__ R3,
                                             const float* __restrict__ gam,
                                             const float* __restrict__ bet,
                                             float* __restrict__ outf,
                                             u16* __restrict__ outb) {
    __shared__ float ws1[4], ws2[4];
    const int row = blockIdx.x, tid = threadIdx.x;
    const size_t ro = (size_t)row * D_;
    float4 v = reinterpret_cast<const float4*>(X + ro)[tid];
    {
        ushort4 r = reinterpret_cast<const ushort4*>(R0 + ro)[tid];
        v.x += b2f(r.x); v.y += b2f(r.y); v.z += b2f(r.z); v.w += b2f(r.w);
    }
    {
        ushort4 r = reinterpret_cast<const ushort4*>(R1 + ro)[tid];
        v.x += b2f(r.x); v.y += b2f(r.y); v.z += b2f(r.z); v.w += b2f(r.w);
    }
    {
        ushort4 r = reinterpret_cast<const ushort4*>(R2 + ro)[tid];
        v.x += b2f(r.x); v.y += b2f(r.y); v.z += b2f(r.z); v.w += b2f(r.w);
    }
    {
        ushort4 r = reinterpret_cast<const ushort4*>(R3 + ro)[tid];
        v.x += b2f(r.x); v.y += b2f(r.y); v.z += b2f(r.z); v.w += b2f(r.w);
    }

    float s = v.x + v.y + v.z + v.w;
#pragma unroll
    for (int m = 32; m >= 1; m >>= 1) s += __shfl_xor(s, m, 64);
    if ((tid & 63) == 0) ws1[tid >> 6] = s;
    __syncthreads();
    float mean = (ws1[0] + ws1[1] + ws1[2] + ws1[3]) * (1.f / D_);

    float4 d; d.x = v.x - mean; d.y = v.y - mean; d.z = v.z - mean; d.w = v.w - mean;
    float q = d.x * d.x + d.y * d.y + d.z * d.z + d.w * d.w;
#pragma unroll
    for (int m = 32; m >= 1; m >>= 1) q += __shfl_xor(q, m, 64);
    if ((tid & 63) == 0) ws2[tid >> 6] = q;
    __syncthreads();
    float var = (ws2[0] + ws2[1] + ws2[2] + ws2[3]) * (1.f / (D_ - 1));
    float inv = 1.f / (sqrtf(var) + 1e-6f);

    const float4 g = reinterpret_cast<const float4*>(gam)[tid];
    const float4 bb = reinterpret_cast<const float4*>(bet)[tid];
    float4 o;
    o.x = g.x * d.x * inv + bb.x;
    o.y = g.y * d.y * inv + bb.y;
    o.z = g.z * d.z * inv + bb.z;
    o.w = g.w * d.w * inv + bb.w;
    if (outf) reinterpret_cast<float4*>(outf + ro)[tid] = o;
    if (outb) {
        ushort4 ob;
        ob.x = f2bf(o.x); ob.y = f2bf(o.y); ob.z = f2bf(o.z); ob.w = f2bf(o.w);
        reinterpret_cast<ushort4*>(outb + ro)[tid] = ob;
    }
}

// ---------------- launcher ----------------
extern "C" void kernel_launch(void* const* d_in, const int* in_sizes, int n_in,
                              void* d_out, int out_size, void* d_ws, size_t ws_size,
                              hipStream_t stream) {
    const float* x    = (const float*)d_in[0];
    const int*   mask = (const int*)d_in[1];
    const float* wq   = (const float*)d_in[2];
    const float* bq   = (const float*)d_in[3];
    const float* wk   = (const float*)d_in[4];
    const float* bk   = (const float*)d_in[5];
    const float* wv   = (const float*)d_in[6];
    const float* bv   = (const float*)d_in[7];
    const float* wo   = (const float*)d_in[8];
    const float* bo   = (const float*)d_in[9];
    const float* g1   = (const float*)d_in[10];
    const float* b1   = (const float*)d_in[11];
    const float* g2   = (const float*)d_in[12];
    const float* b2   = (const float*)d_in[13];
    const float* w1   = (const float*)d_in[14];
    const float* bf1  = (const float*)d_in[15];
    const float* w2   = (const float*)d_in[16];
    const float* bf2  = (const float*)d_in[17];
    float* out = (float*)d_out;

    char* ws = (char*)d_ws;
    const size_t MB = 1u << 20;
    // Transient region (0..72 MB):
    //   xb@0 (8, dead after QKV), wqkvb@8 (6, dead after QKV),
    //   qkvb@14 (24, dead after attn), cvb@64 (8, dead after proj),
    //   pp@0 (32, bf16 proj partials; dead after LN1),
    //   qpart@0 (32, bf16 FFN2 partials; dead after LN2)
    u16*   xb    = (u16*)  (ws + 0 * MB);
    u16*   wqkvb = (u16*)  (ws + 8 * MB);
    u16*   qkvb  = (u16*)  (ws + 14 * MB);
    u16*   cvb   = (u16*)  (ws + 64 * MB);
    u16*   pp    = (u16*)  (ws + 0 * MB);
    u16*   qpart = (u16*)  (ws + 0 * MB);
    // Persistent region (72..147 MB):
    u16*   wob   = (u16*)  (ws + 72 * MB);
    u16*   w1b   = (u16*)  (ws + 74 * MB);
    u16*   w2b   = (u16*)  (ws + 82 * MB);
    float* bqkv  = (float*)(ws + 90 * MB);
    float* mbias = (float*)(ws + 90 * MB + 65536);
    float* hdf   = (float*)(ws + 91 * MB);
    u16*   hdb   = (u16*)  (ws + 107 * MB);
    u16*   ff1b  = (u16*)  (ws + 115 * MB);   // ends 147 MB

    cvt_all<<<2048, 256, 0, stream>>>(x, wq, wk, wv, wo, w1, w2,
                                      bq, bk, bv, mask,
                                      xb, wqkvb, wob, w1b, w2b, bqkv, mbias);

    // fused QKV projection: [4096,3072,1024] on 256x256 8-phase
    gemm256_bt<0><<<dim3(M_ / 256, 3 * D_ / 256, 1), 512, 0, stream>>>(
        xb, wqkvb, bqkv, qkvb, 3 * D_, D_);

    // attention: 8 waves, 128 q-rows per block (measured-best: 71.3 us)
    attn_kernel<<<dim3(S_ / 128, B_ * H_), 512, 0, stream>>>(qkvb, mbias, cvb);

    // output projection: [4096,1024,1024] split-K4 -> bf16 partials pp[0..3]
    gemm256_bt<1><<<dim3(M_ / 256, D_ / 256, 4), 512, 0, stream>>>(
        cvb, wob, bo, pp, D_, D_);

    // residual + LN1: hd = LN(x + pp0..pp3)
    ln_bf<<<M_, 256, 0, stream>>>(x, pp, pp + (size_t)M_ * D_,
                                  pp + 2 * (size_t)M_ * D_,
                                  pp + 3 * (size_t)M_ * D_,
                                  g1, b1, hdf, hdb);

    // FFN1 + GELU: [4096,4096,1024] on 256x256 8-phase
    gemm256_bt<2><<<dim3(M_ / 256, DFF_ / 256, 1), 512, 0, stream>>>(
        hdb, w1b, bf1, ff1b, DFF_, D_);

    // FFN2: [4096,1024,4096] split-K4 -> bf16 partials qpart[0..3]
    gemm256_bt<1><<<dim3(M_ / 256, D_ / 256, 4), 512, 0, stream>>>(
        ff1b, w2b, bf2, qpart, D_, DFF_);

    // residual + LN2 -> out = LN(hdf + q0..q3)
    ln_bf<<<M_, 256, 0, stream>>>(hdf, qpart, qpart + (size_t)M_ * D_,
                                  qpart + 2 * (size_t)M_ * D_,
                                  qpart + 3 * (size_t)M_ * D_,
                                  g2, b2, out, nullptr);
}